// Round 3
// baseline (358.198 us; speedup 1.0000x reference)
//
#include <hip/hip_runtime.h>
#include <cstdint>
#include <cstddef>

// Problem constants
#define BB 8
#define SS 2048
#define DD 512

typedef __attribute__((ext_vector_type(8))) short bf16x8;
typedef __attribute__((ext_vector_type(4))) float f32x4;

__device__ __forceinline__ unsigned short f2bf(float f) {
  unsigned int u = __builtin_bit_cast(unsigned int, f);
  u = (u + 0x7FFFu + ((u >> 16) & 1u)) >> 16;  // RNE
  return (unsigned short)u;
}
__device__ __forceinline__ float bf2f(unsigned short s) {
  return __builtin_bit_cast(float, ((unsigned int)s) << 16);
}

__device__ __forceinline__ void gload_lds16(const unsigned short* g, unsigned short* l) {
  __builtin_amdgcn_global_load_lds(
      (const __attribute__((address_space(1))) void*)g,
      (__attribute__((address_space(3))) void*)l, 16, 0, 0);
}

// ---------------------------------------------------------------------------
// 128x128-tile bf16 GEMM mainloop (m97 structure) — used by qkv projection.
// A[M,K] row-major, B[N,K] row-major (B^T input). 4 waves 2x2, BK=32.
// ---------------------------------------------------------------------------
__device__ __forceinline__ void gemm_tile(
    const unsigned short* __restrict__ A,
    const unsigned short* __restrict__ B,
    int K, unsigned short* lA, unsigned short* lB,
    f32x4 acc[4][4], size_t m0, size_t n0)
{
  const int t = threadIdx.x;
  const int l = t & 63;
  const int w = t >> 6;
  const int wr = w >> 1, wc = w & 1;
  const size_t K64 = (size_t)K * 64;

  const unsigned short* gA = A + (m0 + (size_t)(t >> 2)) * (size_t)K + (size_t)((t & 3) * 8);
  const unsigned short* gB = B + (n0 + (size_t)(t >> 2)) * (size_t)K + (size_t)((t & 3) * 8);

  const int ar = (wr * 64 + (l & 15)) * 32 + (l >> 4) * 8;
  const int br = (wc * 64 + (l & 15)) * 32 + (l >> 4) * 8;

  const int nk = K >> 5;
  int buf = 0;

  gload_lds16(gA, lA + t * 8);
  gload_lds16(gA + K64, lA + 2048 + t * 8);
  gload_lds16(gB, lB + t * 8);
  gload_lds16(gB + K64, lB + 2048 + t * 8);

  for (int kt = 0; kt < nk; ++kt) {
    __syncthreads();
    if (kt + 1 < nk) {
      const int ko = (kt + 1) << 5;
      const int lo = (buf ^ 1) * 4096;
      gload_lds16(gA + ko, lA + lo + t * 8);
      gload_lds16(gA + ko + K64, lA + lo + 2048 + t * 8);
      gload_lds16(gB + ko, lB + lo + t * 8);
      gload_lds16(gB + ko + K64, lB + lo + 2048 + t * 8);
    }
    const unsigned short* pa = lA + buf * 4096 + ar;
    const unsigned short* pb = lB + buf * 4096 + br;
    bf16x8 af[4], bfr[4];
#pragma unroll
    for (int m = 0; m < 4; ++m) af[m] = *(const bf16x8*)(pa + m * 512);
#pragma unroll
    for (int n = 0; n < 4; ++n) bfr[n] = *(const bf16x8*)(pb + n * 512);
#pragma unroll
    for (int m = 0; m < 4; ++m)
#pragma unroll
      for (int n = 0; n < 4; ++n)
        acc[m][n] = __builtin_amdgcn_mfma_f32_16x16x32_bf16(af[m], bfr[n], acc[m][n], 0, 0, 0);
    buf ^= 1;
  }
}

// ---------------------------------------------------------------------------
// Kernel 1: convert X and Wq|Wk|Wv fp32 -> bf16 into ws.
// ---------------------------------------------------------------------------
__global__ __launch_bounds__(256) void convert_k(
    const float* __restrict__ X, const float* __restrict__ Wq,
    const float* __restrict__ Wk, const float* __restrict__ Wv,
    unsigned short* __restrict__ dst)
{
  const size_t NXe = (size_t)BB * SS * DD;  // 8388608
  const size_t NWe = (size_t)DD * DD;       // 262144
  size_t i = ((size_t)blockIdx.x * 256 + threadIdx.x) * 4;
  const float* src;
  size_t off;
  if (i < NXe)                { src = X;  off = i; }
  else if (i < NXe + NWe)     { src = Wq; off = i - NXe; }
  else if (i < NXe + 2 * NWe) { src = Wk; off = i - NXe - NWe; }
  else                        { src = Wv; off = i - NXe - 2 * NWe; }
  float4 f = *(const float4*)(src + off);
  ushort4 o;
  o.x = f2bf(f.x); o.y = f2bf(f.y); o.z = f2bf(f.z); o.w = f2bf(f.w);
  *(ushort4*)(dst + i) = o;
}

// ---------------------------------------------------------------------------
// Kernel 2: QKV projections. z=0 -> Q [16384,512], z=1 -> K [16384,512],
// z=2 -> V transposed per batch: Vt[b][d][s].
// ---------------------------------------------------------------------------
__global__ __launch_bounds__(256, 2) void qkv_gemm_k(
    const unsigned short* __restrict__ Xb,
    const unsigned short* __restrict__ Wall,
    unsigned short* __restrict__ Qb,
    unsigned short* __restrict__ Kb,
    unsigned short* __restrict__ Vtb)
{
  __shared__ __align__(16) unsigned short lA[8192];
  __shared__ __align__(16) unsigned short lB[8192];
  const int z = blockIdx.z;
  const unsigned short* Bw = Wall + (size_t)z * (DD * DD);
  const size_t m0 = (size_t)blockIdx.y * 128;
  const size_t n0 = (size_t)blockIdx.x * 128;
  f32x4 acc[4][4];
#pragma unroll
  for (int m = 0; m < 4; ++m)
#pragma unroll
    for (int n = 0; n < 4; ++n) acc[m][n] = (f32x4){0.f, 0.f, 0.f, 0.f};

  gemm_tile(Xb, Bw, DD, lA, lB, acc, m0, n0);

  const int t = threadIdx.x, l = t & 63, w = t >> 6, wr = w >> 1, wc = w & 1;
  const size_t rb = m0 + (size_t)(wr * 64 + ((l >> 4) * 4));
  const int cb = (int)n0 + wc * 64 + (l & 15);
  if (z < 2) {
    unsigned short* O = z ? Kb : Qb;
#pragma unroll
    for (int m = 0; m < 4; ++m)
#pragma unroll
      for (int n = 0; n < 4; ++n)
#pragma unroll
        for (int j = 0; j < 4; ++j) {
          size_t r = rb + (size_t)(m * 16 + j);
          O[r * DD + (size_t)(cb + n * 16)] = f2bf(acc[m][n][j]);
        }
  } else {
#pragma unroll
    for (int m = 0; m < 4; ++m)
#pragma unroll
      for (int n = 0; n < 4; ++n)
#pragma unroll
        for (int j = 0; j < 4; ++j) {
          size_t r = rb + (size_t)(m * 16 + j);
          size_t bb = r >> 11, s = r & 2047;
          Vtb[((bb * DD + (size_t)(cb + n * 16)) << 11) + s] = f2bf(acc[m][n][j]);
        }
  }
}

// ---------------------------------------------------------------------------
// Kernel 3 (fused flash attention): per block 64 q-rows of one batch.
// 4 waves; each wave owns 16 q-rows -> all online-softmax stats wave-local.
// KV loop: 64 iters of 32 keys. K tile [32 keys][512 d] and V tile
// [512 d][32 k] double-buffered in LDS (global_load_lds, linear dest +
// pre-swizzled source + swizzled read). Q in registers. P through 1 KB
// wave-private LDS (transpose to A-frag layout). O in 128 regs, /l epilogue.
//
// LDS swizzles (involutions, 16B-slot XOR):
//   K [32][512]: slot' = slot ^ (key & 7)        (row = 1024 B, 64 slots)
//   V [512][32]: slot' = slot ^ ((d >> 1) & 3)   (row = 64 B, 4 slots)
//   P [16][32] : slot' = slot ^ ((q >> 1) & 3)   (row = 64 B, 4 slots)
// ---------------------------------------------------------------------------
__device__ __forceinline__ void stage_K(const unsigned short* __restrict__ Kg,
                                        int kt, unsigned short* dst, int t) {
#pragma unroll
  for (int p = 0; p < 8; ++p) {
    int row = 4 * p + (t >> 6);                 // key row 0..31
    int lslot = (t & 63) ^ (row & 7);           // pre-swizzled source slot
    gload_lds16(Kg + (size_t)(kt * 32 + row) * DD + lslot * 8,
                dst + p * 2048 + t * 8);
  }
}

__device__ __forceinline__ void stage_V(const unsigned short* __restrict__ Vg,
                                        int kt, unsigned short* dst, int t) {
#pragma unroll
  for (int p = 0; p < 8; ++p) {
    int d = 64 * p + (t >> 2);                  // d row 0..511
    int lslot = (t & 3) ^ ((d >> 1) & 3);
    gload_lds16(Vg + (size_t)d * SS + kt * 32 + lslot * 8,
                dst + p * 2048 + t * 8);
  }
}

__global__ __launch_bounds__(256, 1) void fused_attn_k(
    const unsigned short* __restrict__ Qb,
    const unsigned short* __restrict__ Kb,
    const unsigned short* __restrict__ Vtb,
    const int* __restrict__ mask,
    float* __restrict__ Out)
{
  __shared__ __align__(16) unsigned short Kl[2][32 * 512];   // 64 KB
  __shared__ __align__(16) unsigned short Vl[2][512 * 32];   // 64 KB
  __shared__ __align__(16) unsigned short Pl[4][16 * 32];    // 4 KB

  const int t = threadIdx.x;
  const int l = t & 63;
  const int w = t >> 6;
  const int b = blockIdx.y;
  const size_t bs0 = (size_t)b * SS + (size_t)blockIdx.x * 64;

  const unsigned short* Qg = Qb + (bs0 + (size_t)(w * 16)) * DD;
  const unsigned short* Kg = Kb + (size_t)b * ((size_t)SS * DD);
  const unsigned short* Vg = Vtb + (size_t)b * ((size_t)DD * SS);
  const int* mk = mask + ((size_t)b << 11);

  // Q fragments: wave's 16 q-rows, 16 k-steps of 32
  bf16x8 qf[16];
  {
    const unsigned short* qrow = Qg + (size_t)(l & 15) * DD + (l >> 4) * 8;
#pragma unroll
    for (int ks = 0; ks < 16; ++ks) qf[ks] = *(const bf16x8*)(qrow + ks * 32);
  }

  f32x4 oacc[32];
#pragma unroll
  for (int fn = 0; fn < 32; ++fn) oacc[fn] = (f32x4){0.f, 0.f, 0.f, 0.f};
  float mrow[4] = {-1e30f, -1e30f, -1e30f, -1e30f};
  float lrow[4] = {0.f, 0.f, 0.f, 0.f};

  const float SCALE = 0.022097086912079608f;  // 1/sqrt(2048)

  stage_K(Kg, 0, Kl[0], t);
  stage_V(Vg, 0, Vl[0], t);

  int buf = 0;
  for (int kt = 0; kt < 64; ++kt) {
    __syncthreads();  // stage(kt) complete; buf^1 free
    if (kt + 1 < 64) {
      stage_K(Kg, kt + 1, Kl[buf ^ 1], t);
      stage_V(Vg, kt + 1, Vl[buf ^ 1], t);
    }

    // ---- S = Q . K^T : 2 n-frags x 16 k-steps
    f32x4 sacc[2];
    sacc[0] = (f32x4){0.f, 0.f, 0.f, 0.f};
    sacc[1] = (f32x4){0.f, 0.f, 0.f, 0.f};
    const unsigned short* Kc = Kl[buf];
#pragma unroll
    for (int fn = 0; fn < 2; ++fn) {
      const int key = fn * 16 + (l & 15);
      const unsigned short* krow = Kc + key * 512;
      const int kx = key & 7;
#pragma unroll
      for (int ks = 0; ks < 16; ++ks) {
        int slot = ks * 4 + (l >> 4);
        bf16x8 kf = *(const bf16x8*)(krow + ((slot ^ kx) * 8));
        sacc[fn] = __builtin_amdgcn_mfma_f32_16x16x32_bf16(qf[ks], kf, sacc[fn], 0, 0, 0);
      }
    }

    // ---- masked online softmax (rows (l>>4)*4+j, wave-local)
    const int mk0 = mk[kt * 32 + (l & 15)];
    const int mk1 = mk[kt * 32 + 16 + (l & 15)];
    float scl[4];
    unsigned short p0[4], p1[4];
#pragma unroll
    for (int j = 0; j < 4; ++j) {
      float s0 = mk0 ? sacc[0][j] * SCALE : -1e30f;
      float s1 = mk1 ? sacc[1][j] * SCALE : -1e30f;
      float mx = fmaxf(s0, s1);
      mx = fmaxf(mx, __shfl_xor(mx, 1));
      mx = fmaxf(mx, __shfl_xor(mx, 2));
      mx = fmaxf(mx, __shfl_xor(mx, 4));
      mx = fmaxf(mx, __shfl_xor(mx, 8));
      float mnew = fmaxf(mrow[j], mx);
      scl[j] = __expf(mrow[j] - mnew);
      mrow[j] = mnew;
      float e0 = mk0 ? __expf(s0 - mnew) : 0.f;
      float e1 = mk1 ? __expf(s1 - mnew) : 0.f;
      float r = e0 + e1;
      r += __shfl_xor(r, 1);
      r += __shfl_xor(r, 2);
      r += __shfl_xor(r, 4);
      r += __shfl_xor(r, 8);
      lrow[j] = lrow[j] * scl[j] + r;
      p0[j] = f2bf(e0);
      p1[j] = f2bf(e1);
    }

    // rescale O accumulator
#pragma unroll
    for (int fn = 0; fn < 32; ++fn)
#pragma unroll
      for (int j = 0; j < 4; ++j) oacc[fn][j] *= scl[j];

    // ---- P -> wave-private LDS (transpose to A-frag layout, swizzled)
    unsigned short* Pw = Pl[w];
#pragma unroll
    for (int j = 0; j < 4; ++j) {
      int row = (l >> 4) * 4 + j;               // q-local
      int x = ((row >> 1) & 3) << 3;            // element-space slot XOR
      Pw[row * 32 + (((l & 15)) ^ x)]      = p0[j];
      Pw[row * 32 + ((16 + (l & 15)) ^ x)] = p1[j];
    }
    bf16x8 pf;
    {
      int row = l & 15;                          // q-local for A-frag
      int slot = (l >> 4) ^ ((row >> 1) & 3);
      pf = *(const bf16x8*)(Pw + row * 32 + slot * 8);
    }

    // ---- O += P . V : 32 n-frags (d), 1 k-step
    const unsigned short* Vc = Vl[buf];
#pragma unroll
    for (int fn = 0; fn < 32; ++fn) {
      int d = fn * 16 + (l & 15);
      int slot = (l >> 4) ^ ((d >> 1) & 3);
      bf16x8 vf = *(const bf16x8*)(Vc + d * 32 + slot * 8);
      oacc[fn] = __builtin_amdgcn_mfma_f32_16x16x32_bf16(pf, vf, oacc[fn], 0, 0, 0);
    }
    buf ^= 1;
  }

  // ---- epilogue: O / l -> fp32 out
  float inv[4];
#pragma unroll
  for (int j = 0; j < 4; ++j) inv[j] = 1.f / lrow[j];
  float* Og = Out + (bs0 + (size_t)(w * 16)) * DD;
#pragma unroll
  for (int fn = 0; fn < 32; ++fn) {
    int d = fn * 16 + (l & 15);
#pragma unroll
    for (int j = 0; j < 4; ++j) {
      int row = (l >> 4) * 4 + j;
      Og[(size_t)row * DD + d] = oacc[fn][j] * inv[j];
    }
  }
}

// ---------------------------------------------------------------------------
// Workspace layout (ushort elements):
//   Xb   @ 0         : 8388608   (bf16 X)
//   Wall @ 8388608   : 786432    (bf16 Wq|Wk|Wv)
//   Qb   @ 9175040   : 8388608
//   Kb   @ 17563648  : 8388608
//   Vtb  @ 25952256  : 8388608   ([b][d][s])
// ---------------------------------------------------------------------------
extern "C" void kernel_launch(void* const* d_in, const int* in_sizes, int n_in,
                              void* d_out, int out_size, void* d_ws, size_t ws_size,
                              hipStream_t stream) {
  const float* X    = (const float*)d_in[0];
  const int*   mask = (const int*)d_in[1];
  const float* Wq   = (const float*)d_in[2];
  const float* Wk   = (const float*)d_in[3];
  const float* Wv   = (const float*)d_in[4];

  unsigned short* ws   = (unsigned short*)d_ws;
  unsigned short* Xb   = ws;
  unsigned short* Wall = ws + 8388608;
  unsigned short* Qb   = ws + 9175040;
  unsigned short* Kb   = ws + 17563648;
  unsigned short* Vtb  = ws + 25952256;
  float* Out = (float*)d_out;

  // 1) fp32 -> bf16 conversion
  convert_k<<<8960, 256, 0, stream>>>(X, Wq, Wk, Wv, ws);

  // 2) Q/K/V projections
  qkv_gemm_k<<<dim3(4, 128, 3), 256, 0, stream>>>(Xb, Wall, Qb, Kb, Vtb);

  // 3) fused flash attention (scores + masked softmax + PV)
  fused_attn_k<<<dim3(32, 8), 256, 0, stream>>>(Qb, Kb, Vtb, mask, Out);
}

// Round 4
// 357.129 us; speedup vs baseline: 1.0030x; 1.0030x over previous
//
#include <hip/hip_runtime.h>
#include <cstdint>
#include <cstddef>

// Problem constants
#define BB 8
#define SS 2048
#define DD 512

typedef __attribute__((ext_vector_type(8))) short bf16x8;
typedef __attribute__((ext_vector_type(4))) float f32x4;
typedef __attribute__((ext_vector_type(4))) unsigned int u32x4;

__device__ __forceinline__ unsigned short f2bf(float f) {
  unsigned int u = __builtin_bit_cast(unsigned int, f);
  u = (u + 0x7FFFu + ((u >> 16) & 1u)) >> 16;  // RNE
  return (unsigned short)u;
}
__device__ __forceinline__ float bf2f(unsigned short s) {
  return __builtin_bit_cast(float, ((unsigned int)s) << 16);
}

__device__ __forceinline__ void gload_lds16(const unsigned short* g, unsigned short* l) {
  __builtin_amdgcn_global_load_lds(
      (const __attribute__((address_space(1))) void*)g,
      (__attribute__((address_space(3))) void*)l, 16, 0, 0);
}

// ---------------------------------------------------------------------------
// 128x128-tile bf16 GEMM mainloop (m97 structure) — used by qkv projection.
// ---------------------------------------------------------------------------
__device__ __forceinline__ void gemm_tile(
    const unsigned short* __restrict__ A,
    const unsigned short* __restrict__ B,
    int K, unsigned short* lA, unsigned short* lB,
    f32x4 acc[4][4], size_t m0, size_t n0)
{
  const int t = threadIdx.x;
  const int l = t & 63;
  const int w = t >> 6;
  const int wr = w >> 1, wc = w & 1;
  const size_t K64 = (size_t)K * 64;

  const unsigned short* gA = A + (m0 + (size_t)(t >> 2)) * (size_t)K + (size_t)((t & 3) * 8);
  const unsigned short* gB = B + (n0 + (size_t)(t >> 2)) * (size_t)K + (size_t)((t & 3) * 8);

  const int ar = (wr * 64 + (l & 15)) * 32 + (l >> 4) * 8;
  const int br = (wc * 64 + (l & 15)) * 32 + (l >> 4) * 8;

  const int nk = K >> 5;
  int buf = 0;

  gload_lds16(gA, lA + t * 8);
  gload_lds16(gA + K64, lA + 2048 + t * 8);
  gload_lds16(gB, lB + t * 8);
  gload_lds16(gB + K64, lB + 2048 + t * 8);

  for (int kt = 0; kt < nk; ++kt) {
    __syncthreads();
    if (kt + 1 < nk) {
      const int ko = (kt + 1) << 5;
      const int lo = (buf ^ 1) * 4096;
      gload_lds16(gA + ko, lA + lo + t * 8);
      gload_lds16(gA + ko + K64, lA + lo + 2048 + t * 8);
      gload_lds16(gB + ko, lB + lo + t * 8);
      gload_lds16(gB + ko + K64, lB + lo + 2048 + t * 8);
    }
    const unsigned short* pa = lA + buf * 4096 + ar;
    const unsigned short* pb = lB + buf * 4096 + br;
    bf16x8 af[4], bfr[4];
#pragma unroll
    for (int m = 0; m < 4; ++m) af[m] = *(const bf16x8*)(pa + m * 512);
#pragma unroll
    for (int n = 0; n < 4; ++n) bfr[n] = *(const bf16x8*)(pb + n * 512);
#pragma unroll
    for (int m = 0; m < 4; ++m)
#pragma unroll
      for (int n = 0; n < 4; ++n)
        acc[m][n] = __builtin_amdgcn_mfma_f32_16x16x32_bf16(af[m], bfr[n], acc[m][n], 0, 0, 0);
    buf ^= 1;
  }
}

// ---------------------------------------------------------------------------
// Kernel 1: convert X and Wq|Wk|Wv fp32 -> bf16 into ws.
// ---------------------------------------------------------------------------
__global__ __launch_bounds__(256) void convert_k(
    const float* __restrict__ X, const float* __restrict__ Wq,
    const float* __restrict__ Wk, const float* __restrict__ Wv,
    unsigned short* __restrict__ dst)
{
  const size_t NXe = (size_t)BB * SS * DD;  // 8388608
  const size_t NWe = (size_t)DD * DD;       // 262144
  size_t i = ((size_t)blockIdx.x * 256 + threadIdx.x) * 4;
  const float* src;
  size_t off;
  if (i < NXe)                { src = X;  off = i; }
  else if (i < NXe + NWe)     { src = Wq; off = i - NXe; }
  else if (i < NXe + 2 * NWe) { src = Wk; off = i - NXe - NWe; }
  else                        { src = Wv; off = i - NXe - 2 * NWe; }
  float4 f = *(const float4*)(src + off);
  ushort4 o;
  o.x = f2bf(f.x); o.y = f2bf(f.y); o.z = f2bf(f.z); o.w = f2bf(f.w);
  *(ushort4*)(dst + i) = o;
}

// ---------------------------------------------------------------------------
// Kernel 2: QKV projections. z=0 -> Q [16384,512], z=1 -> K [16384,512],
// z=2 -> V transposed per batch: Vt[b][d][s].
// ---------------------------------------------------------------------------
__global__ __launch_bounds__(256, 2) void qkv_gemm_k(
    const unsigned short* __restrict__ Xb,
    const unsigned short* __restrict__ Wall,
    unsigned short* __restrict__ Qb,
    unsigned short* __restrict__ Kb,
    unsigned short* __restrict__ Vtb)
{
  __shared__ __align__(16) unsigned short lA[8192];
  __shared__ __align__(16) unsigned short lB[8192];
  const int z = blockIdx.z;
  const unsigned short* Bw = Wall + (size_t)z * (DD * DD);
  const size_t m0 = (size_t)blockIdx.y * 128;
  const size_t n0 = (size_t)blockIdx.x * 128;
  f32x4 acc[4][4];
#pragma unroll
  for (int m = 0; m < 4; ++m)
#pragma unroll
    for (int n = 0; n < 4; ++n) acc[m][n] = (f32x4){0.f, 0.f, 0.f, 0.f};

  gemm_tile(Xb, Bw, DD, lA, lB, acc, m0, n0);

  const int t = threadIdx.x, l = t & 63, w = t >> 6, wr = w >> 1, wc = w & 1;
  const size_t rb = m0 + (size_t)(wr * 64 + ((l >> 4) * 4));
  const int cb = (int)n0 + wc * 64 + (l & 15);
  if (z < 2) {
    unsigned short* O = z ? Kb : Qb;
#pragma unroll
    for (int m = 0; m < 4; ++m)
#pragma unroll
      for (int n = 0; n < 4; ++n)
#pragma unroll
        for (int j = 0; j < 4; ++j) {
          size_t r = rb + (size_t)(m * 16 + j);
          O[r * DD + (size_t)(cb + n * 16)] = f2bf(acc[m][n][j]);
        }
  } else {
#pragma unroll
    for (int m = 0; m < 4; ++m)
#pragma unroll
      for (int n = 0; n < 4; ++n)
#pragma unroll
        for (int j = 0; j < 4; ++j) {
          size_t r = rb + (size_t)(m * 16 + j);
          size_t bb = r >> 11, s = r & 2047;
          Vtb[((bb * DD + (size_t)(cb + n * 16)) << 11) + s] = f2bf(acc[m][n][j]);
        }
  }
}

// ---------------------------------------------------------------------------
// Kernel 3 (fused flash attention, phase-split waves):
// 256 blocks (1/CU), 4 waves, 64 q-rows/block, KVBLK=32, single-buffered LDS.
//   QK+softmax: wave w owns q-rows [w*16, w*16+16) (r3-verified layout).
//   PV: wave w owns d-slice [w*128, w*128+128) of ALL 64 q-rows, reading the
//       shared P[64][32] from LDS (4 P-frags + 8 V-frags per 32 MFMAs).
// K staged via global_load_lds issued after bar B (hides under PV).
// V reg-staged: global->reg issued after QK, reg->LDS after bar A (T14).
// Defer-max (T13) gates the O-rescale via per-wave flags in LDS.
// XCD-aligned: b = blockIdx.x & 7 (same-batch blocks share an XCD's L2).
//
// LDS swizzles (involutions on 16B slots, all r3-verified):
//   K [32][512]: slot' = slot ^ (key & 7)
//   V [512][32]: slot' = slot ^ ((d >> 1) & 3)
//   P [64][32] : slot' = slot ^ ((q >> 1) & 3)
// ---------------------------------------------------------------------------
__device__ __forceinline__ void stage_K(const unsigned short* __restrict__ Kg,
                                        int kt, unsigned short* dst, int t) {
#pragma unroll
  for (int p = 0; p < 8; ++p) {
    int row = 4 * p + (t >> 6);                 // key row 0..31
    int lslot = (t & 63) ^ (row & 7);           // pre-swizzled source slot
    gload_lds16(Kg + (size_t)(kt * 32 + row) * DD + lslot * 8,
                dst + p * 2048 + t * 8);
  }
}

__global__ __launch_bounds__(256, 1) void fused_attn_k(
    const unsigned short* __restrict__ Qb,
    const unsigned short* __restrict__ Kb,
    const unsigned short* __restrict__ Vtb,
    const int* __restrict__ mask,
    float* __restrict__ Out)
{
  __shared__ __align__(16) unsigned short Kl[32 * 512];   // 32 KB
  __shared__ __align__(16) unsigned short Vl[512 * 32];   // 32 KB
  __shared__ __align__(16) unsigned short Pl[64 * 32];    // 4 KB
  __shared__ float sclS[64];
  __shared__ float linvS[64];
  __shared__ int flagS[4];

  const int t = threadIdx.x;
  const int l = t & 63;
  const int w = t >> 6;
  const int b = blockIdx.x & 7;                 // batch -> XCD aligned
  const int qt = blockIdx.x >> 3;
  const size_t bs0 = (size_t)b * SS + (size_t)qt * 64;

  const unsigned short* Qg = Qb + (bs0 + (size_t)(w * 16)) * DD;
  const unsigned short* Kg = Kb + (size_t)b * ((size_t)SS * DD);
  const unsigned short* Vg = Vtb + (size_t)b * ((size_t)DD * SS);
  const int* mk = mask + ((size_t)b << 11);

  // Q fragments: wave's 16 q-rows, 16 k-steps of 32
  bf16x8 qf[16];
  {
    const unsigned short* qrow = Qg + (size_t)(l & 15) * DD + (l >> 4) * 8;
#pragma unroll
    for (int ks = 0; ks < 16; ++ks) qf[ks] = *(const bf16x8*)(qrow + ks * 32);
  }

  f32x4 oacc[32];
#pragma unroll
  for (int fn = 0; fn < 32; ++fn) oacc[fn] = (f32x4){0.f, 0.f, 0.f, 0.f};
  float mrow[4] = {-1e30f, -1e30f, -1e30f, -1e30f};
  float lrow[4] = {0.f, 0.f, 0.f, 0.f};

  const float SCALE = 0.022097086912079608f;    // 1/sqrt(2048)

  // V chunk mapping: thread t handles (d = 64p + (t>>2), slot = t&3)
  const int vd = t >> 2;
  const int vs = t & 3;

  // prologue: V[0] -> regs, K[0] -> LDS
  u32x4 vr[8];
#pragma unroll
  for (int p = 0; p < 8; ++p) {
    int d = 64 * p + vd;
    vr[p] = *(const u32x4*)(Vg + (size_t)d * SS + vs * 8);
  }
  stage_K(Kg, 0, Kl, t);

  for (int kt = 0; kt < 64; ++kt) {
    __syncthreads();  // bar A: K[kt] staged, V[kt] regs ready, prev PV done

    // ---- V[kt]: regs -> LDS (swizzled write)
#pragma unroll
    for (int p = 0; p < 8; ++p) {
      int d = 64 * p + vd;
      int s2 = vs ^ ((d >> 1) & 3);
      *(u32x4*)(Vl + d * 32 + s2 * 8) = vr[p];
    }

    // ---- QK: wave w -> S[16 q][32 k]
    f32x4 sacc[2];
    sacc[0] = (f32x4){0.f, 0.f, 0.f, 0.f};
    sacc[1] = (f32x4){0.f, 0.f, 0.f, 0.f};
    __builtin_amdgcn_s_setprio(1);
#pragma unroll
    for (int fn = 0; fn < 2; ++fn) {
      const int key = fn * 16 + (l & 15);
      const unsigned short* krow = Kl + key * 512;
      const int kx = key & 7;
#pragma unroll
      for (int ks = 0; ks < 16; ++ks) {
        int slot = ks * 4 + (l >> 4);
        bf16x8 kf = *(const bf16x8*)(krow + ((slot ^ kx) * 8));
        sacc[fn] = __builtin_amdgcn_mfma_f32_16x16x32_bf16(qf[ks], kf, sacc[fn], 0, 0, 0);
      }
    }
    __builtin_amdgcn_s_setprio(0);

    // ---- issue V[kt+1] global loads (latency hides under softmax+PV)
    if (kt + 1 < 64) {
#pragma unroll
      for (int p = 0; p < 8; ++p) {
        int d = 64 * p + vd;
        vr[p] = *(const u32x4*)(Vg + (size_t)d * SS + (size_t)((kt + 1) * 32) + vs * 8);
      }
    }

    // ---- masked online softmax with defer-max (rows (l>>4)*4+j of wave w)
    const int mk0 = mk[kt * 32 + (l & 15)];
    const int mk1 = mk[kt * 32 + 16 + (l & 15)];
    float s0[4], s1[4], pmax[4];
    bool need = false;
#pragma unroll
    for (int j = 0; j < 4; ++j) {
      s0[j] = mk0 ? sacc[0][j] * SCALE : -1e30f;
      s1[j] = mk1 ? sacc[1][j] * SCALE : -1e30f;
      float mx = fmaxf(s0[j], s1[j]);
      mx = fmaxf(mx, __shfl_xor(mx, 1));
      mx = fmaxf(mx, __shfl_xor(mx, 2));
      mx = fmaxf(mx, __shfl_xor(mx, 4));
      mx = fmaxf(mx, __shfl_xor(mx, 8));
      pmax[j] = mx;
      need = need || (mx > mrow[j] + 8.f);
    }
    need = (bool)__any((int)need);
    float sclj[4] = {1.f, 1.f, 1.f, 1.f};
    if (need) {
#pragma unroll
      for (int j = 0; j < 4; ++j) {
        float mnew = fmaxf(mrow[j], pmax[j]);
        sclj[j] = __expf(mrow[j] - mnew);
        mrow[j] = mnew;
        lrow[j] *= sclj[j];
      }
    }
    unsigned short p0[4], p1[4];
#pragma unroll
    for (int j = 0; j < 4; ++j) {
      float e0 = mk0 ? __expf(s0[j] - mrow[j]) : 0.f;
      float e1 = mk1 ? __expf(s1[j] - mrow[j]) : 0.f;
      float r = e0 + e1;
      r += __shfl_xor(r, 1);
      r += __shfl_xor(r, 2);
      r += __shfl_xor(r, 4);
      r += __shfl_xor(r, 8);
      lrow[j] += r;
      p0[j] = f2bf(e0);
      p1[j] = f2bf(e1);
    }
    // P -> LDS (rows w*16.., swizzled)
#pragma unroll
    for (int j = 0; j < 4; ++j) {
      int row = w * 16 + (l >> 4) * 4 + j;
      int x = ((row >> 1) & 3) << 3;
      Pl[row * 32 + (((l & 15)) ^ x)]      = p0[j];
      Pl[row * 32 + ((16 + (l & 15)) ^ x)] = p1[j];
    }
    if ((l & 15) == 0) {
#pragma unroll
      for (int j = 0; j < 4; ++j) sclS[w * 16 + (l >> 4) * 4 + j] = sclj[j];
      if (l == 0) flagS[w] = need ? 1 : 0;
    }

    __syncthreads();  // bar B: P/scl/flags visible; K buffer free

    // ---- issue K[kt+1] -> LDS (hides under PV)
    if (kt + 1 < 64) stage_K(Kg, kt + 1, Kl, t);

    // ---- PV: wave w -> O[64 q][d-slice w*128..+128)
    int needR = flagS[0] | flagS[1] | flagS[2] | flagS[3];
    if (needR) {
#pragma unroll
      for (int m = 0; m < 4; ++m) {
        f32x4 sv = *(const f32x4*)(sclS + m * 16 + (l >> 4) * 4);
#pragma unroll
        for (int n = 0; n < 8; ++n)
#pragma unroll
          for (int j = 0; j < 4; ++j) oacc[m * 8 + n][j] *= sv[j];
      }
    }
    bf16x8 pa[4];
#pragma unroll
    for (int m = 0; m < 4; ++m) {
      int row = m * 16 + (l & 15);
      int slot = (l >> 4) ^ ((row >> 1) & 3);
      pa[m] = *(const bf16x8*)(Pl + row * 32 + slot * 8);
    }
    __builtin_amdgcn_s_setprio(1);
#pragma unroll
    for (int n = 0; n < 8; ++n) {
      int d = w * 128 + n * 16 + (l & 15);
      int vslot = (l >> 4) ^ ((d >> 1) & 3);
      bf16x8 vf = *(const bf16x8*)(Vl + d * 32 + vslot * 8);
#pragma unroll
      for (int m = 0; m < 4; ++m)
        oacc[m * 8 + n] = __builtin_amdgcn_mfma_f32_16x16x32_bf16(pa[m], vf, oacc[m * 8 + n], 0, 0, 0);
    }
    __builtin_amdgcn_s_setprio(0);
  }

  // ---- epilogue: broadcast 1/l, write O
  if ((l & 15) == 0) {
#pragma unroll
    for (int j = 0; j < 4; ++j)
      linvS[w * 16 + (l >> 4) * 4 + j] = 1.f / lrow[j];
  }
  __syncthreads();
  float* Og = Out + bs0 * DD;
#pragma unroll
  for (int m = 0; m < 4; ++m) {
    f32x4 li = *(const f32x4*)(linvS + m * 16 + (l >> 4) * 4);
#pragma unroll
    for (int n = 0; n < 8; ++n) {
      int d = w * 128 + n * 16 + (l & 15);
#pragma unroll
      for (int j = 0; j < 4; ++j) {
        int q = m * 16 + (l >> 4) * 4 + j;
        Og[(size_t)q * DD + d] = oacc[m * 8 + n][j] * li[j];
      }
    }
  }
}

// ---------------------------------------------------------------------------
// Workspace layout (ushort elements):
//   Xb   @ 0         : 8388608   (bf16 X)
//   Wall @ 8388608   : 786432    (bf16 Wq|Wk|Wv)
//   Qb   @ 9175040   : 8388608
//   Kb   @ 17563648  : 8388608
//   Vtb  @ 25952256  : 8388608   ([b][d][s])
// ---------------------------------------------------------------------------
extern "C" void kernel_launch(void* const* d_in, const int* in_sizes, int n_in,
                              void* d_out, int out_size, void* d_ws, size_t ws_size,
                              hipStream_t stream) {
  const float* X    = (const float*)d_in[0];
  const int*   mask = (const int*)d_in[1];
  const float* Wq   = (const float*)d_in[2];
  const float* Wk   = (const float*)d_in[3];
  const float* Wv   = (const float*)d_in[4];

  unsigned short* ws   = (unsigned short*)d_ws;
  unsigned short* Xb   = ws;
  unsigned short* Wall = ws + 8388608;
  unsigned short* Qb   = ws + 9175040;
  unsigned short* Kb   = ws + 17563648;
  unsigned short* Vtb  = ws + 25952256;
  float* Out = (float*)d_out;

  // 1) fp32 -> bf16 conversion
  convert_k<<<8960, 256, 0, stream>>>(X, Wq, Wk, Wv, ws);

  // 2) Q/K/V projections
  qkv_gemm_k<<<dim3(4, 128, 3), 256, 0, stream>>>(Xb, Wall, Qb, Kb, Vtb);

  // 3) fused flash attention (scores + masked softmax + PV)
  fused_attn_k<<<256, 256, 0, stream>>>(Qb, Kb, Vtb, mask, Out);
}